// Round 5
// baseline (2015.527 us; speedup 1.0000x reference)
//
#include <hip/hip_runtime.h>

typedef short short8 __attribute__((ext_vector_type(8)));
typedef __bf16 bf16x8 __attribute__((ext_vector_type(8)));
typedef float f32x4 __attribute__((ext_vector_type(4)));

#define FEAT 128
#define FPL 2048

__device__ __forceinline__ float b2f(unsigned int u) {
  union { unsigned int u; float f; } c; c.u = u << 16; return c.f;
}
__device__ __forceinline__ unsigned short f2b(float f) {
  union { float f; unsigned int u; } c; c.f = f;
  unsigned int r = c.u + 0x7fffu + ((c.u >> 16) & 1u);
  return (unsigned short)(r >> 16);
}
__device__ __forceinline__ f32x4 mfma16(short8 a, short8 b, f32x4 c) {
  return __builtin_amdgcn_mfma_f32_16x16x32_bf16(
      __builtin_bit_cast(bf16x8, a), __builtin_bit_cast(bf16x8, b), c, 0, 0, 0);
}

// ---- conversion kernels ----
__global__ void cvt_kernel(const float* __restrict__ in, unsigned short* __restrict__ out, int n2) {
  int i = blockIdx.x * 256 + threadIdx.x;
  if (i < n2) {
    float2 v = ((const float2*)in)[i];
    unsigned int lo = f2b(v.x), hi = f2b(v.y);
    ((unsigned int*)out)[i] = lo | (hi << 16);
  }
}

// W[K][N] (row-major) -> WT[N][K] bf16
__global__ void cvtT_kernel(const float* __restrict__ W, unsigned short* __restrict__ WT, int K, int N) {
  int i = blockIdx.x * 256 + threadIdx.x;
  if (i < K * N) {
    int k = i / N, c = i - k * N;
    WT[(size_t)c * K + k] = f2b(W[i]);
  }
}

// ---- CSR build ----
__global__ void count_kernel(const int* __restrict__ dst, int* __restrict__ cnt, int n) {
  int i = blockIdx.x * 256 + threadIdx.x;
  if (i < n) atomicAdd(&cnt[dst[i]], 1);
}

__global__ __launch_bounds__(1024) void scan_kernel(const int* __restrict__ cnt, int* __restrict__ rp, int n) {
  __shared__ int sd[1024];
  __shared__ int carry;
  if (threadIdx.x == 0) carry = 0;
  __syncthreads();
  for (int base = 0; base < n; base += 1024) {
    int i = base + (int)threadIdx.x;
    int v = (i < n) ? cnt[i] : 0;
    sd[threadIdx.x] = v;
    __syncthreads();
    int sum = v;
    for (int off = 1; off < 1024; off <<= 1) {
      int t = (threadIdx.x >= (unsigned)off) ? sd[threadIdx.x - off] : 0;
      __syncthreads();
      sum += t;
      sd[threadIdx.x] = sum;
      __syncthreads();
    }
    if (i < n) rp[i] = carry + sum - v;  // exclusive
    __syncthreads();
    if (threadIdx.x == 1023) carry += sum;
    __syncthreads();
  }
  if (threadIdx.x == 0) rp[n] = carry;
}

__global__ void copy_kernel(const int* __restrict__ a, int* __restrict__ b, int n) {
  int i = blockIdx.x * 256 + threadIdx.x;
  if (i < n) b[i] = a[i];
}

__global__ void fill_kernel(const int* __restrict__ src, const int* __restrict__ dst,
                            int* __restrict__ cursor, int* __restrict__ col, int n) {
  int i = blockIdx.x * 256 + threadIdx.x;
  if (i < n) {
    int p = atomicAdd(&cursor[dst[i]], 1);
    col[p] = src[i];
  }
}

// ---- neighbor gather: agg[i] = x[i] + sum_{j in N(i)} x[j], bf16 in/out, fp32 accum ----
__global__ __launch_bounds__(256) void gather_kernel(const unsigned short* __restrict__ x,
    const int* __restrict__ rp, const int* __restrict__ col,
    unsigned short* __restrict__ agg, int n) {
  int wid = (blockIdx.x * 256 + threadIdx.x) >> 6;
  int lane = threadIdx.x & 63;
  if (wid >= n) return;
  const unsigned int* xw = (const unsigned int*)x;
  unsigned int s = xw[(size_t)wid * 64 + lane];
  float ax = b2f(s & 0xffffu), ay = b2f(s >> 16);
  int beg = rp[wid], end = rp[wid + 1];
  int j = beg;
  for (; j + 4 <= end; j += 4) {
    int c0 = col[j], c1 = col[j + 1], c2 = col[j + 2], c3 = col[j + 3];
    unsigned int v0 = xw[(size_t)c0 * 64 + lane];
    unsigned int v1 = xw[(size_t)c1 * 64 + lane];
    unsigned int v2 = xw[(size_t)c2 * 64 + lane];
    unsigned int v3 = xw[(size_t)c3 * 64 + lane];
    ax += b2f(v0 & 0xffffu) + b2f(v1 & 0xffffu) + b2f(v2 & 0xffffu) + b2f(v3 & 0xffffu);
    ay += b2f(v0 >> 16) + b2f(v1 >> 16) + b2f(v2 >> 16) + b2f(v3 >> 16);
  }
  for (; j < end; ++j) {
    unsigned int v = xw[(size_t)col[j] * 64 + lane];
    ax += b2f(v & 0xffffu);
    ay += b2f(v >> 16);
  }
  ((unsigned int*)agg)[(size_t)wid * 64 + lane] = (unsigned int)f2b(ax) | ((unsigned int)f2b(ay) << 16);
}

// ---- GEMM1: H = relu(A @ W1 + b1), [n,128]x[128,128], bf16 in/out ----
__global__ __launch_bounds__(256) void gemm1_kernel(
    const unsigned short* __restrict__ A, const unsigned short* __restrict__ W1T,
    const float* __restrict__ b1, unsigned short* __restrict__ H, int n) {
  const int wave = threadIdx.x >> 6;
  const int lane = threadIdx.x & 63;
  const int lr = lane & 15, lg = lane >> 4;
  const int rowBase = blockIdx.x * 64 + wave * 16;
  short8 a[4];
#pragma unroll
  for (int kt = 0; kt < 4; ++kt)
    a[kt] = *(const short8*)(A + (size_t)(rowBase + lr) * FEAT + kt * 32 + lg * 8);
  f32x4 acc[8];
#pragma unroll
  for (int ct = 0; ct < 8; ++ct) {
    const unsigned short* bp = W1T + (size_t)(ct * 16 + lr) * FEAT + lg * 8;
    f32x4 c = {0.f, 0.f, 0.f, 0.f};
    c = mfma16(a[0], *(const short8*)(bp), c);
    c = mfma16(a[1], *(const short8*)(bp + 32), c);
    c = mfma16(a[2], *(const short8*)(bp + 64), c);
    c = mfma16(a[3], *(const short8*)(bp + 96), c);
    acc[ct] = c;
  }
#pragma unroll
  for (int ct = 0; ct < 8; ++ct) {
    const int c = ct * 16 + lr;
    const float bias = b1[c];
#pragma unroll
    for (int j = 0; j < 4; ++j) {
      const int row = rowBase + lg * 4 + j;
      if (row < n) {
        float v = acc[ct][j] + bias;
        H[(size_t)row * FEAT + c] = f2b(v > 0.f ? v : 0.f);
      }
    }
  }
}

// ---- statT: per-row softmax stats T[r] = max + ln(sum exp(l - max)) ----
// 512 threads = 8 waves; each wave: 16 rows x all 2048 cols, online (m,s) in
// registers only (no logit storage, no LDS). Live set ~60 VGPR -> no spill,
// high occupancy. Rounds 1-4 showed any structure holding the 2048-wide logit
// tile (regs OR LDS) is spill- or latency-bound; recompute is cheaper.
__global__ __launch_bounds__(512) void statT_kernel(
    const unsigned short* __restrict__ H, const unsigned short* __restrict__ W2T,
    const float* __restrict__ b2, float* __restrict__ T, int n) {
  const int wave = threadIdx.x >> 6;
  const int lane = threadIdx.x & 63;
  const int lr = lane & 15, lg = lane >> 4;
  const int rowBase = blockIdx.x * 128 + wave * 16;
  short8 a[4];
#pragma unroll
  for (int kt = 0; kt < 4; ++kt)
    a[kt] = *(const short8*)(H + (size_t)(rowBase + lr) * FEAT + kt * 32 + lg * 8);

  float m[4] = {-1e30f, -1e30f, -1e30f, -1e30f};
  float s[4] = {0.f, 0.f, 0.f, 0.f};
#pragma unroll 2
  for (int ct = 0; ct < FPL / 16; ++ct) {
    const unsigned short* bp = W2T + (size_t)(ct * 16 + lr) * FEAT + lg * 8;
    f32x4 c = {0.f, 0.f, 0.f, 0.f};
    c = mfma16(a[0], *(const short8*)(bp), c);
    c = mfma16(a[1], *(const short8*)(bp + 32), c);
    c = mfma16(a[2], *(const short8*)(bp + 64), c);
    c = mfma16(a[3], *(const short8*)(bp + 96), c);
    const float bias = b2[ct * 16 + lr];
#pragma unroll
    for (int j = 0; j < 4; ++j) {
      float e = c[j] + bias;
      float nm = fmaxf(m[j], e);
      s[j] = s[j] * __expf(m[j] - nm) + __expf(e - nm);
      m[j] = nm;
    }
  }
  // merge across the 16 lanes (lr bits) holding different col slices of same rows
#pragma unroll
  for (int j = 0; j < 4; ++j) {
#pragma unroll
    for (int d = 1; d < 16; d <<= 1) {
      float om = __shfl_xor(m[j], d, 64);
      float os = __shfl_xor(s[j], d, 64);
      float nm = fmaxf(m[j], om);
      s[j] = s[j] * __expf(m[j] - nm) + os * __expf(om - nm);
      m[j] = nm;
    }
  }
  if (lr == 0) {
#pragma unroll
    for (int j = 0; j < 4; ++j) {
      const int row = rowBase + lg * 4 + j;
      if (row < n) T[row] = m[j] + __logf(s[j]);
    }
  }
}

// ---- fpacc: recompute logits, fp_partial[c] += sum_r exp(l[r,c] - T[r]) ----
// 512 threads = 8 waves; block = 128 rows x 2048 cols; 8 KB LDS fp tile.
__global__ __launch_bounds__(512) void fpacc_kernel(
    const unsigned short* __restrict__ H, const unsigned short* __restrict__ W2T,
    const float* __restrict__ b2, const float* __restrict__ T,
    float* __restrict__ partials, int n) {
  __shared__ float fp_lds[FPL];
  const int wave = threadIdx.x >> 6;
  const int lane = threadIdx.x & 63;
  const int lr = lane & 15, lg = lane >> 4;
  const int rowBase = blockIdx.x * 128 + wave * 16;
  for (int i = threadIdx.x; i < FPL; i += 512) fp_lds[i] = 0.f;

  short8 a[4];
#pragma unroll
  for (int kt = 0; kt < 4; ++kt)
    a[kt] = *(const short8*)(H + (size_t)(rowBase + lr) * FEAT + kt * 32 + lg * 8);
  float Tj[4];
#pragma unroll
  for (int j = 0; j < 4; ++j) {
    const int row = rowBase + lg * 4 + j;
    Tj[j] = (row < n) ? T[row] : 1e30f;  // pad rows contribute exp(-huge)=0
  }
  __syncthreads();

#pragma unroll 2
  for (int ct = 0; ct < FPL / 16; ++ct) {
    const unsigned short* bp = W2T + (size_t)(ct * 16 + lr) * FEAT + lg * 8;
    f32x4 c = {0.f, 0.f, 0.f, 0.f};
    c = mfma16(a[0], *(const short8*)(bp), c);
    c = mfma16(a[1], *(const short8*)(bp + 32), c);
    c = mfma16(a[2], *(const short8*)(bp + 64), c);
    c = mfma16(a[3], *(const short8*)(bp + 96), c);
    const float bias = b2[ct * 16 + lr];
    float p = __expf(c[0] + bias - Tj[0]) + __expf(c[1] + bias - Tj[1]) +
              __expf(c[2] + bias - Tj[2]) + __expf(c[3] + bias - Tj[3]);
    p += __shfl_xor(p, 16, 64);
    p += __shfl_xor(p, 32, 64);
    if (lg == 0) atomicAdd(&fp_lds[ct * 16 + lr], p);
  }
  __syncthreads();
  for (int i = threadIdx.x; i < FPL; i += 512)
    partials[(size_t)blockIdx.x * FPL + i] += fp_lds[i];
}

__global__ void reduce_kernel(const float* __restrict__ partials, float* __restrict__ out, int nPart) {
  int c = blockIdx.x * 256 + threadIdx.x;
  if (c < FPL) {
    float s = 0.f;
    for (int p = 0; p < nPart; ++p) s += partials[(size_t)p * FPL + c];
    out[c] = s;
  }
}

extern "C" void kernel_launch(void* const* d_in, const int* in_sizes, int n_in,
                              void* d_out, int out_size, void* d_ws, size_t ws_size,
                              hipStream_t stream) {
  const float* atoms = (const float*)d_in[0];
  const float* W1 = (const float*)d_in[1];
  const float* b1 = (const float*)d_in[2];
  const float* W2 = (const float*)d_in[3];
  const float* b2 = (const float*)d_in[4];
  const int* esrc = (const int*)d_in[5];
  const int* edst = (const int*)d_in[6];
  const int nAtoms = in_sizes[0] / FEAT;
  const int nEdges = in_sizes[5];
  if (nAtoms <= 0) return;

  const int g2Blocks = (nAtoms + 127) / 128;  // 128-row tiles for statT/fpacc
  const int nPad = g2Blocks * 128;
  const int g1Blocks = nPad / 64;

  size_t off = 0;
  auto alloc = [&](size_t bytes) -> void* {
    void* p = (char*)d_ws + off;
    off += (bytes + 255) & ~(size_t)255;
    return p;
  };
  unsigned short* P = (unsigned short*)alloc((size_t)nPad * FEAT * 2);
  unsigned short* Q = (unsigned short*)alloc((size_t)nPad * FEAT * 2);
  unsigned short* W1T = (unsigned short*)alloc((size_t)FEAT * FEAT * 2);
  unsigned short* W2T = (unsigned short*)alloc((size_t)FEAT * FPL * 2);
  int* counts = (int*)alloc((size_t)nAtoms * 4);
  int* cursor = (int*)alloc((size_t)nAtoms * 4);
  int* rp = (int*)alloc(((size_t)nAtoms + 1) * 4);
  int* col = (int*)alloc((size_t)nEdges * 4);
  float* Trow = (float*)alloc((size_t)nPad * 4);
  float* partials = (float*)alloc((size_t)g2Blocks * FPL * 4);

  hipMemsetAsync(counts, 0, (size_t)nAtoms * 4, stream);
  hipMemsetAsync(partials, 0, (size_t)g2Blocks * FPL * 4, stream);
  hipMemsetAsync(P + (size_t)nAtoms * FEAT, 0, (size_t)(nPad - nAtoms) * FEAT * 2, stream);
  hipMemsetAsync(Q + (size_t)nAtoms * FEAT, 0, (size_t)(nPad - nAtoms) * FEAT * 2, stream);

  const int n2 = in_sizes[0] / 2;
  cvt_kernel<<<(n2 + 255) / 256, 256, 0, stream>>>(atoms, P, n2);
  cvtT_kernel<<<(FEAT * FEAT + 255) / 256, 256, 0, stream>>>(W1, W1T, FEAT, FEAT);
  cvtT_kernel<<<(FEAT * FPL + 255) / 256, 256, 0, stream>>>(W2, W2T, FEAT, FPL);
  count_kernel<<<(nEdges + 255) / 256, 256, 0, stream>>>(edst, counts, nEdges);
  scan_kernel<<<1, 1024, 0, stream>>>(counts, rp, nAtoms);
  copy_kernel<<<(nAtoms + 255) / 256, 256, 0, stream>>>(rp, cursor, nAtoms);
  fill_kernel<<<(nEdges + 255) / 256, 256, 0, stream>>>(esrc, edst, cursor, col, nEdges);

  unsigned short* x = P;
  unsigned short* y = Q;
  for (int step = 0; step < 3; ++step) {
    gather_kernel<<<(nAtoms + 3) / 4, 256, 0, stream>>>(x, rp, col, y, nAtoms);
    gemm1_kernel<<<g1Blocks, 256, 0, stream>>>(y, W1T, b1, y, nAtoms);
    statT_kernel<<<g2Blocks, 512, 0, stream>>>(y, W2T, b2, Trow, nAtoms);
    fpacc_kernel<<<g2Blocks, 512, 0, stream>>>(y, W2T, b2, Trow, partials, nAtoms);
    unsigned short* t = x; x = y; y = t;
  }
  reduce_kernel<<<(FPL + 255) / 256, 256, 0, stream>>>(partials, (float*)d_out, g2Blocks);
}

// Round 6
// 1879.242 us; speedup vs baseline: 1.0725x; 1.0725x over previous
//
#include <hip/hip_runtime.h>

typedef short short8 __attribute__((ext_vector_type(8)));
typedef __bf16 bf16x8 __attribute__((ext_vector_type(8)));
typedef float f32x4 __attribute__((ext_vector_type(4)));

#define FEAT 128
#define FPL 2048

__device__ __forceinline__ float b2f(unsigned int u) {
  union { unsigned int u; float f; } c; c.u = u << 16; return c.f;
}
__device__ __forceinline__ unsigned short f2b(float f) {
  union { float f; unsigned int u; } c; c.f = f;
  unsigned int r = c.u + 0x7fffu + ((c.u >> 16) & 1u);
  return (unsigned short)(r >> 16);
}
__device__ __forceinline__ f32x4 mfma16(short8 a, short8 b, f32x4 c) {
  return __builtin_amdgcn_mfma_f32_16x16x32_bf16(
      __builtin_bit_cast(bf16x8, a), __builtin_bit_cast(bf16x8, b), c, 0, 0, 0);
}

// ---- conversion kernels ----
__global__ void cvt_kernel(const float* __restrict__ in, unsigned short* __restrict__ out, int n2) {
  int i = blockIdx.x * 256 + threadIdx.x;
  if (i < n2) {
    float2 v = ((const float2*)in)[i];
    unsigned int lo = f2b(v.x), hi = f2b(v.y);
    ((unsigned int*)out)[i] = lo | (hi << 16);
  }
}

// W[K][N] (row-major) -> WT[N][K] bf16
__global__ void cvtT_kernel(const float* __restrict__ W, unsigned short* __restrict__ WT, int K, int N) {
  int i = blockIdx.x * 256 + threadIdx.x;
  if (i < K * N) {
    int k = i / N, c = i - k * N;
    WT[(size_t)c * K + k] = f2b(W[i]);
  }
}

// ---- CSR build ----
__global__ void count_kernel(const int* __restrict__ dst, int* __restrict__ cnt, int n) {
  int i = blockIdx.x * 256 + threadIdx.x;
  if (i < n) atomicAdd(&cnt[dst[i]], 1);
}

__global__ __launch_bounds__(1024) void scan_kernel(const int* __restrict__ cnt, int* __restrict__ rp, int n) {
  __shared__ int sd[1024];
  __shared__ int carry;
  if (threadIdx.x == 0) carry = 0;
  __syncthreads();
  for (int base = 0; base < n; base += 1024) {
    int i = base + (int)threadIdx.x;
    int v = (i < n) ? cnt[i] : 0;
    sd[threadIdx.x] = v;
    __syncthreads();
    int sum = v;
    for (int off = 1; off < 1024; off <<= 1) {
      int t = (threadIdx.x >= (unsigned)off) ? sd[threadIdx.x - off] : 0;
      __syncthreads();
      sum += t;
      sd[threadIdx.x] = sum;
      __syncthreads();
    }
    if (i < n) rp[i] = carry + sum - v;  // exclusive
    __syncthreads();
    if (threadIdx.x == 1023) carry += sum;
    __syncthreads();
  }
  if (threadIdx.x == 0) rp[n] = carry;
}

__global__ void copy_kernel(const int* __restrict__ a, int* __restrict__ b, int n) {
  int i = blockIdx.x * 256 + threadIdx.x;
  if (i < n) b[i] = a[i];
}

__global__ void fill_kernel(const int* __restrict__ src, const int* __restrict__ dst,
                            int* __restrict__ cursor, int* __restrict__ col, int n) {
  int i = blockIdx.x * 256 + threadIdx.x;
  if (i < n) {
    int p = atomicAdd(&cursor[dst[i]], 1);
    col[p] = src[i];
  }
}

// ---- neighbor gather: agg[i] = x[i] + sum_{j in N(i)} x[j], bf16 in/out, fp32 accum ----
__global__ __launch_bounds__(256) void gather_kernel(const unsigned short* __restrict__ x,
    const int* __restrict__ rp, const int* __restrict__ col,
    unsigned short* __restrict__ agg, int n) {
  int wid = (blockIdx.x * 256 + threadIdx.x) >> 6;
  int lane = threadIdx.x & 63;
  if (wid >= n) return;
  const unsigned int* xw = (const unsigned int*)x;
  unsigned int s = xw[(size_t)wid * 64 + lane];
  float ax = b2f(s & 0xffffu), ay = b2f(s >> 16);
  int beg = rp[wid], end = rp[wid + 1];
  int j = beg;
  for (; j + 4 <= end; j += 4) {
    int c0 = col[j], c1 = col[j + 1], c2 = col[j + 2], c3 = col[j + 3];
    unsigned int v0 = xw[(size_t)c0 * 64 + lane];
    unsigned int v1 = xw[(size_t)c1 * 64 + lane];
    unsigned int v2 = xw[(size_t)c2 * 64 + lane];
    unsigned int v3 = xw[(size_t)c3 * 64 + lane];
    ax += b2f(v0 & 0xffffu) + b2f(v1 & 0xffffu) + b2f(v2 & 0xffffu) + b2f(v3 & 0xffffu);
    ay += b2f(v0 >> 16) + b2f(v1 >> 16) + b2f(v2 >> 16) + b2f(v3 >> 16);
  }
  for (; j < end; ++j) {
    unsigned int v = xw[(size_t)col[j] * 64 + lane];
    ax += b2f(v & 0xffffu);
    ay += b2f(v >> 16);
  }
  ((unsigned int*)agg)[(size_t)wid * 64 + lane] = (unsigned int)f2b(ax) | ((unsigned int)f2b(ay) << 16);
}

// ---- GEMM1: H = relu(A @ W1 + b1), [n,128]x[128,128], bf16 in/out ----
__global__ __launch_bounds__(256) void gemm1_kernel(
    const unsigned short* __restrict__ A, const unsigned short* __restrict__ W1T,
    const float* __restrict__ b1, unsigned short* __restrict__ H, int n) {
  const int wave = threadIdx.x >> 6;
  const int lane = threadIdx.x & 63;
  const int lr = lane & 15, lg = lane >> 4;
  const int rowBase = blockIdx.x * 64 + wave * 16;
  short8 a[4];
#pragma unroll
  for (int kt = 0; kt < 4; ++kt)
    a[kt] = *(const short8*)(A + (size_t)(rowBase + lr) * FEAT + kt * 32 + lg * 8);
  f32x4 acc[8];
#pragma unroll
  for (int ct = 0; ct < 8; ++ct) {
    const unsigned short* bp = W1T + (size_t)(ct * 16 + lr) * FEAT + lg * 8;
    f32x4 c = {0.f, 0.f, 0.f, 0.f};
    c = mfma16(a[0], *(const short8*)(bp), c);
    c = mfma16(a[1], *(const short8*)(bp + 32), c);
    c = mfma16(a[2], *(const short8*)(bp + 64), c);
    c = mfma16(a[3], *(const short8*)(bp + 96), c);
    acc[ct] = c;
  }
#pragma unroll
  for (int ct = 0; ct < 8; ++ct) {
    const int c = ct * 16 + lr;
    const float bias = b1[c];
#pragma unroll
    for (int j = 0; j < 4; ++j) {
      const int row = rowBase + lg * 4 + j;
      if (row < n) {
        float v = acc[ct][j] + bias;
        H[(size_t)row * FEAT + c] = f2b(v > 0.f ? v : 0.f);
      }
    }
  }
}

// ---- statT: partial per-row softmax stats over a 512-col slice ----
// grid = nRowBlk x 4 col-slices; block = 128 rows x 512 cols; wave = 16 rows.
// Defer-max online update (rescale only when max grows by >8) keeps the hot
// loop to 1 exp + 1 add per element with no serial rescale chain.
__global__ __launch_bounds__(512) void statT_kernel(
    const unsigned short* __restrict__ H, const unsigned short* __restrict__ W2T,
    const float* __restrict__ b2, float* __restrict__ pm, float* __restrict__ ps,
    int nPad) {
  const int wave = threadIdx.x >> 6;
  const int lane = threadIdx.x & 63;
  const int lr = lane & 15, lg = lane >> 4;
  const int nRowBlk = nPad >> 7;
  const int rowBlk = blockIdx.x % nRowBlk;
  const int colBlk = blockIdx.x / nRowBlk;
  const int rowBase = rowBlk * 128 + wave * 16;
  const int colBase = colBlk * 512;

  short8 a[4];
#pragma unroll
  for (int kt = 0; kt < 4; ++kt)
    a[kt] = *(const short8*)(H + (size_t)(rowBase + lr) * FEAT + kt * 32 + lg * 8);

  float m[4] = {-1e30f, -1e30f, -1e30f, -1e30f};
  float s[4] = {0.f, 0.f, 0.f, 0.f};
#pragma unroll 2
  for (int ct = 0; ct < 32; ++ct) {
    const unsigned short* bp = W2T + (size_t)(colBase + ct * 16 + lr) * FEAT + lg * 8;
    f32x4 c0 = {0.f, 0.f, 0.f, 0.f};
    f32x4 c1 = {0.f, 0.f, 0.f, 0.f};
    c0 = mfma16(a[0], *(const short8*)(bp), c0);
    c1 = mfma16(a[1], *(const short8*)(bp + 32), c1);
    c0 = mfma16(a[2], *(const short8*)(bp + 64), c0);
    c1 = mfma16(a[3], *(const short8*)(bp + 96), c1);
    const float bias = b2[colBase + ct * 16 + lr];
    float e[4];
#pragma unroll
    for (int j = 0; j < 4; ++j) e[j] = c0[j] + c1[j] + bias;
    bool need = (e[0] > m[0] + 8.f) || (e[1] > m[1] + 8.f) ||
                (e[2] > m[2] + 8.f) || (e[3] > m[3] + 8.f);
    if (__any(need)) {
#pragma unroll
      for (int j = 0; j < 4; ++j) {
        float nm = fmaxf(m[j], e[j]);
        s[j] = s[j] * __expf(m[j] - nm) + __expf(e[j] - nm);
        m[j] = nm;
      }
    } else {
#pragma unroll
      for (int j = 0; j < 4; ++j) s[j] += __expf(e[j] - m[j]);
    }
  }
  // merge across the 16 lr lanes (distinct col sub-slices of the same rows)
#pragma unroll
  for (int j = 0; j < 4; ++j) {
#pragma unroll
    for (int d = 1; d < 16; d <<= 1) {
      float om = __shfl_xor(m[j], d, 64);
      float os = __shfl_xor(s[j], d, 64);
      float nm = fmaxf(m[j], om);
      s[j] = s[j] * __expf(m[j] - nm) + os * __expf(om - nm);
      m[j] = nm;
    }
  }
  if (lr == 0) {
#pragma unroll
    for (int j = 0; j < 4; ++j) {
      const int row = rowBase + lg * 4 + j;
      pm[(size_t)colBlk * nPad + row] = m[j];
      ps[(size_t)colBlk * nPad + row] = s[j];
    }
  }
}

// ---- mergeT: T[r] = M + ln(sum_k s_k * exp(m_k - M)) over the 4 col-slices ----
__global__ void mergeT_kernel(const float* __restrict__ pm, const float* __restrict__ ps,
                              float* __restrict__ T, int nPad) {
  int r = blockIdx.x * 256 + threadIdx.x;
  if (r < nPad) {
    float M = pm[r];
#pragma unroll
    for (int k = 1; k < 4; ++k) M = fmaxf(M, pm[(size_t)k * nPad + r]);
    float S = 0.f;
#pragma unroll
    for (int k = 0; k < 4; ++k) S += ps[(size_t)k * nPad + r] * __expf(pm[(size_t)k * nPad + r] - M);
    T[r] = M + __logf(S);
  }
}

// ---- fpacc: recompute logits, fp_partial[c] += sum_r exp(l[r,c] - T[r]) ----
// same row x col split as statT; per-wave plain LDS writes (no atomics).
__global__ __launch_bounds__(512) void fpacc_kernel(
    const unsigned short* __restrict__ H, const unsigned short* __restrict__ W2T,
    const float* __restrict__ b2, const float* __restrict__ T,
    float* __restrict__ partials, int n, int nPad) {
  __shared__ float fp_w[8][512];
  const int wave = threadIdx.x >> 6;
  const int lane = threadIdx.x & 63;
  const int lr = lane & 15, lg = lane >> 4;
  const int nRowBlk = nPad >> 7;
  const int rowBlk = blockIdx.x % nRowBlk;
  const int colBlk = blockIdx.x / nRowBlk;
  const int rowBase = rowBlk * 128 + wave * 16;
  const int colBase = colBlk * 512;

  short8 a[4];
#pragma unroll
  for (int kt = 0; kt < 4; ++kt)
    a[kt] = *(const short8*)(H + (size_t)(rowBase + lr) * FEAT + kt * 32 + lg * 8);
  float Tj[4];
#pragma unroll
  for (int j = 0; j < 4; ++j) {
    const int row = rowBase + lg * 4 + j;
    Tj[j] = (row < n) ? T[row] : 1e30f;  // pad rows contribute 0
  }

#pragma unroll 2
  for (int ct = 0; ct < 32; ++ct) {
    const unsigned short* bp = W2T + (size_t)(colBase + ct * 16 + lr) * FEAT + lg * 8;
    f32x4 c0 = {0.f, 0.f, 0.f, 0.f};
    f32x4 c1 = {0.f, 0.f, 0.f, 0.f};
    c0 = mfma16(a[0], *(const short8*)(bp), c0);
    c1 = mfma16(a[1], *(const short8*)(bp + 32), c1);
    c0 = mfma16(a[2], *(const short8*)(bp + 64), c0);
    c1 = mfma16(a[3], *(const short8*)(bp + 96), c1);
    const float bias = b2[colBase + ct * 16 + lr];
    float p = __expf(c0[0] + c1[0] + bias - Tj[0]) + __expf(c0[1] + c1[1] + bias - Tj[1]) +
              __expf(c0[2] + c1[2] + bias - Tj[2]) + __expf(c0[3] + c1[3] + bias - Tj[3]);
    p += __shfl_xor(p, 16, 64);
    p += __shfl_xor(p, 32, 64);
    if (lg == 0) fp_w[wave][ct * 16 + lr] = p;  // disjoint cols per ct: plain write
  }
  __syncthreads();
  const int i = threadIdx.x;  // 512 threads == 512 cols
  float sum = 0.f;
#pragma unroll
  for (int w = 0; w < 8; ++w) sum += fp_w[w][i];
  partials[(size_t)rowBlk * FPL + colBase + i] += sum;
}

__global__ void reduce_kernel(const float* __restrict__ partials, float* __restrict__ out, int nPart) {
  int c = blockIdx.x * 256 + threadIdx.x;
  if (c < FPL) {
    float s = 0.f;
    for (int p = 0; p < nPart; ++p) s += partials[(size_t)p * FPL + c];
    out[c] = s;
  }
}

extern "C" void kernel_launch(void* const* d_in, const int* in_sizes, int n_in,
                              void* d_out, int out_size, void* d_ws, size_t ws_size,
                              hipStream_t stream) {
  const float* atoms = (const float*)d_in[0];
  const float* W1 = (const float*)d_in[1];
  const float* b1 = (const float*)d_in[2];
  const float* W2 = (const float*)d_in[3];
  const float* b2 = (const float*)d_in[4];
  const int* esrc = (const int*)d_in[5];
  const int* edst = (const int*)d_in[6];
  const int nAtoms = in_sizes[0] / FEAT;
  const int nEdges = in_sizes[5];
  if (nAtoms <= 0) return;

  const int g2Blocks = (nAtoms + 127) / 128;  // 128-row tiles
  const int nPad = g2Blocks * 128;
  const int g1Blocks = nPad / 64;

  size_t off = 0;
  auto alloc = [&](size_t bytes) -> void* {
    void* p = (char*)d_ws + off;
    off += (bytes + 255) & ~(size_t)255;
    return p;
  };
  unsigned short* P = (unsigned short*)alloc((size_t)nPad * FEAT * 2);
  unsigned short* Q = (unsigned short*)alloc((size_t)nPad * FEAT * 2);
  unsigned short* W1T = (unsigned short*)alloc((size_t)FEAT * FEAT * 2);
  unsigned short* W2T = (unsigned short*)alloc((size_t)FEAT * FPL * 2);
  int* counts = (int*)alloc((size_t)nAtoms * 4);
  int* cursor = (int*)alloc((size_t)nAtoms * 4);
  int* rp = (int*)alloc(((size_t)nAtoms + 1) * 4);
  int* col = (int*)alloc((size_t)nEdges * 4);
  float* pm = (float*)alloc((size_t)4 * nPad * 4);
  float* ps = (float*)alloc((size_t)4 * nPad * 4);
  float* Trow = (float*)alloc((size_t)nPad * 4);
  float* partials = (float*)alloc((size_t)g2Blocks * FPL * 4);

  hipMemsetAsync(counts, 0, (size_t)nAtoms * 4, stream);
  hipMemsetAsync(partials, 0, (size_t)g2Blocks * FPL * 4, stream);
  hipMemsetAsync(P + (size_t)nAtoms * FEAT, 0, (size_t)(nPad - nAtoms) * FEAT * 2, stream);
  hipMemsetAsync(Q + (size_t)nAtoms * FEAT, 0, (size_t)(nPad - nAtoms) * FEAT * 2, stream);

  const int n2 = in_sizes[0] / 2;
  cvt_kernel<<<(n2 + 255) / 256, 256, 0, stream>>>(atoms, P, n2);
  cvtT_kernel<<<(FEAT * FEAT + 255) / 256, 256, 0, stream>>>(W1, W1T, FEAT, FEAT);
  cvtT_kernel<<<(FEAT * FPL + 255) / 256, 256, 0, stream>>>(W2, W2T, FEAT, FPL);
  count_kernel<<<(nEdges + 255) / 256, 256, 0, stream>>>(edst, counts, nEdges);
  scan_kernel<<<1, 1024, 0, stream>>>(counts, rp, nAtoms);
  copy_kernel<<<(nAtoms + 255) / 256, 256, 0, stream>>>(rp, cursor, nAtoms);
  fill_kernel<<<(nEdges + 255) / 256, 256, 0, stream>>>(esrc, edst, cursor, col, nEdges);

  unsigned short* x = P;
  unsigned short* y = Q;
  for (int step = 0; step < 3; ++step) {
    gather_kernel<<<(nAtoms + 3) / 4, 256, 0, stream>>>(x, rp, col, y, nAtoms);
    gemm1_kernel<<<g1Blocks, 256, 0, stream>>>(y, W1T, b1, y, nAtoms);
    statT_kernel<<<g2Blocks * 4, 512, 0, stream>>>(y, W2T, b2, pm, ps, nPad);
    mergeT_kernel<<<(nPad + 255) / 256, 256, 0, stream>>>(pm, ps, Trow, nPad);
    fpacc_kernel<<<g2Blocks * 4, 512, 0, stream>>>(y, W2T, b2, Trow, partials, nAtoms, nPad);
    unsigned short* t = x; x = y; y = t;
  }
  reduce_kernel<<<(FPL + 255) / 256, 256, 0, stream>>>(partials, (float*)d_out, g2Blocks);
}